// Round 1
// baseline (125.278 us; speedup 1.0000x reference)
//
#include <hip/hip_runtime.h>

#define EPS_F 1e-8f

static constexpr int B = 32;
static constexpr int S = 512;
static constexpr int D = 768;
static constexpr int O = 2048;

// ---------------- Kernel A: y[b,d] = (1/S) * sum_s x[b,s,d] / max(||x[b,s,:]||, eps)
// One wave per token row (768 floats = 64 lanes x 12). 16 rows per block
// (4 rows/wave), per-wave register accumulators over its 12 d-slots, LDS
// combine across the 4 waves, then one global atomicAdd per d per block.
static constexpr int ROWS_PER_BLOCK = 16;
static constexpr int CHUNKS = S / ROWS_PER_BLOCK;  // 32 -> grid = 32*32 = 1024 blocks

__global__ __launch_bounds__(256)
void mean_norm_kernel(const float* __restrict__ x, float* __restrict__ y) {
    const int bid  = blockIdx.x;
    const int b    = bid / CHUNKS;
    const int c    = bid % CHUNKS;
    const int wave = threadIdx.x >> 6;
    const int lane = threadIdx.x & 63;

    const float* xb = x + ((size_t)b * S + (size_t)c * ROWS_PER_BLOCK) * D;

    float racc[12];
#pragma unroll
    for (int j = 0; j < 12; ++j) racc[j] = 0.0f;

#pragma unroll
    for (int rr = 0; rr < ROWS_PER_BLOCK / 4; ++rr) {
        const int r = rr * 4 + wave;
        const float* row = xb + (size_t)r * D;
        const float4 v0 = *(const float4*)(row + 0 * 256 + lane * 4);
        const float4 v1 = *(const float4*)(row + 1 * 256 + lane * 4);
        const float4 v2 = *(const float4*)(row + 2 * 256 + lane * 4);
        float ssq = v0.x * v0.x + v0.y * v0.y + v0.z * v0.z + v0.w * v0.w
                  + v1.x * v1.x + v1.y * v1.y + v1.z * v1.z + v1.w * v1.w
                  + v2.x * v2.x + v2.y * v2.y + v2.z * v2.z + v2.w * v2.w;
#pragma unroll
        for (int off = 1; off < 64; off <<= 1) ssq += __shfl_xor(ssq, off);
        const float inv = 1.0f / fmaxf(sqrtf(ssq), EPS_F);
        racc[0]  += v0.x * inv;  racc[1]  += v0.y * inv;
        racc[2]  += v0.z * inv;  racc[3]  += v0.w * inv;
        racc[4]  += v1.x * inv;  racc[5]  += v1.y * inv;
        racc[6]  += v1.z * inv;  racc[7]  += v1.w * inv;
        racc[8]  += v2.x * inv;  racc[9]  += v2.y * inv;
        racc[10] += v2.z * inv;  racc[11] += v2.w * inv;
    }

    __shared__ float lacc[4][D];
#pragma unroll
    for (int k = 0; k < 3; ++k) {
        float4 v = make_float4(racc[k * 4 + 0], racc[k * 4 + 1],
                               racc[k * 4 + 2], racc[k * 4 + 3]);
        *(float4*)&lacc[wave][k * 256 + lane * 4] = v;
    }
    __syncthreads();

#pragma unroll
    for (int i = 0; i < 3; ++i) {
        const int d = threadIdx.x * 3 + i;  // 256 threads x 3 = 768
        const float v = lacc[0][d] + lacc[1][d] + lacc[2][d] + lacc[3][d];
        atomicAdd(&y[b * D + d], v * (1.0f / (float)S));
    }
}

// ---------------- Kernel B: out[b,o] = (y[b,:] . p[o,:]) / max(||p[o,:]||, eps)
// Thread = (b in 0..31, oj in 0..3, h in 0..1). h splits D into two 384-halves;
// adjacent lanes (h=0/1) combine via __shfl_xor(.,1). p-row ssq computed
// redundantly in-register (data already loaded), so no separate norm pass.
static constexpr int OJ = 4;            // o-rows per block -> grid = 2048/4 = 512
static constexpr int HALF = D / 2;      // 384

__global__ __launch_bounds__(256)
void proj_kernel(const float* __restrict__ p, const float* __restrict__ y,
                 float* __restrict__ out) {
    const int o0  = blockIdx.x * OJ;
    const int tid = threadIdx.x;
    const int h   = tid & 1;
    const int oj  = (tid >> 1) & (OJ - 1);
    const int b   = tid >> 3;

    const float* prow = p + (size_t)(o0 + oj) * D + h * HALF;
    const float* yrow = y + (size_t)b * D + h * HALF;

    float dot = 0.0f, sp = 0.0f;
#pragma unroll 8
    for (int d = 0; d < HALF; d += 4) {
        const float4 pv = *(const float4*)(prow + d);
        const float4 yv = *(const float4*)(yrow + d);
        dot += pv.x * yv.x + pv.y * yv.y + pv.z * yv.z + pv.w * yv.w;
        sp  += pv.x * pv.x + pv.y * pv.y + pv.z * pv.z + pv.w * pv.w;
    }

    dot += __shfl_xor(dot, 1);
    sp  += __shfl_xor(sp, 1);

    if (h == 0) {
        out[b * O + (o0 + oj)] = dot / fmaxf(sqrtf(sp), EPS_F);
    }
}

extern "C" void kernel_launch(void* const* d_in, const int* in_sizes, int n_in,
                              void* d_out, int out_size, void* d_ws, size_t ws_size,
                              hipStream_t stream) {
    const float* x = (const float*)d_in[0];   // [32, 512, 768] fp32
    const float* p = (const float*)d_in[1];   // [2048, 768] fp32
    float* out = (float*)d_out;               // [32, 2048] fp32
    float* y   = (float*)d_ws;                // [32, 768] fp32 scratch (98304 B)

    // ws is re-poisoned to 0xAA before every call; zero the accumulator.
    hipMemsetAsync(y, 0, (size_t)B * D * sizeof(float), stream);

    mean_norm_kernel<<<B * CHUNKS, 256, 0, stream>>>(x, y);
    proj_kernel<<<O / OJ, 256, 0, stream>>>(p, y, out);
}

// Round 2
// 119.892 us; speedup vs baseline: 1.0449x; 1.0449x over previous
//
#include <hip/hip_runtime.h>

#define EPS_F 1e-8f

static constexpr int B = 32;
static constexpr int S = 512;
static constexpr int D = 768;
static constexpr int O = 2048;

// ---------------- Kernel A: partial sums of normalized rows.
// part[bid][d] = sum over this block's 16 rows of x[b,s,d] / max(||x[b,s]||, eps)
// One wave per token row (768 floats = 64 lanes x 12 = 3 x float4/lane).
// 16 rows per block (4 rows/wave), register accumulators, LDS combine,
// one coalesced float4 store per (block, d/4). NO atomics, NO init required.
static constexpr int ROWS_PER_BLOCK = 16;
static constexpr int CHUNKS = S / ROWS_PER_BLOCK;  // 32 -> grid = 32*32 = 1024 blocks

__global__ __launch_bounds__(256)
void mean_norm_partial_kernel(const float* __restrict__ x, float* __restrict__ part) {
    const int bid  = blockIdx.x;
    const int b    = bid / CHUNKS;
    const int c    = bid % CHUNKS;
    const int wave = threadIdx.x >> 6;
    const int lane = threadIdx.x & 63;

    const float* xb = x + ((size_t)b * S + (size_t)c * ROWS_PER_BLOCK) * D;

    float racc[12];
#pragma unroll
    for (int j = 0; j < 12; ++j) racc[j] = 0.0f;

#pragma unroll
    for (int rr = 0; rr < ROWS_PER_BLOCK / 4; ++rr) {
        const int r = rr * 4 + wave;
        const float* row = xb + (size_t)r * D;
        const float4 v0 = *(const float4*)(row + 0 * 256 + lane * 4);
        const float4 v1 = *(const float4*)(row + 1 * 256 + lane * 4);
        const float4 v2 = *(const float4*)(row + 2 * 256 + lane * 4);
        float ssq = v0.x * v0.x + v0.y * v0.y + v0.z * v0.z + v0.w * v0.w
                  + v1.x * v1.x + v1.y * v1.y + v1.z * v1.z + v1.w * v1.w
                  + v2.x * v2.x + v2.y * v2.y + v2.z * v2.z + v2.w * v2.w;
#pragma unroll
        for (int off = 1; off < 64; off <<= 1) ssq += __shfl_xor(ssq, off);
        const float inv = 1.0f / fmaxf(sqrtf(ssq), EPS_F);
        racc[0]  += v0.x * inv;  racc[1]  += v0.y * inv;
        racc[2]  += v0.z * inv;  racc[3]  += v0.w * inv;
        racc[4]  += v1.x * inv;  racc[5]  += v1.y * inv;
        racc[6]  += v1.z * inv;  racc[7]  += v1.w * inv;
        racc[8]  += v2.x * inv;  racc[9]  += v2.y * inv;
        racc[10] += v2.z * inv;  racc[11] += v2.w * inv;
    }

    __shared__ float lacc[4][D];
#pragma unroll
    for (int k = 0; k < 3; ++k) {
        float4 v = make_float4(racc[k * 4 + 0], racc[k * 4 + 1],
                               racc[k * 4 + 2], racc[k * 4 + 3]);
        *(float4*)&lacc[wave][k * 256 + lane * 4] = v;
    }
    __syncthreads();

    // threads 0..191: each writes one float4 (192*4 = 768), coalesced.
    if (threadIdx.x < D / 4) {
        const int d4 = threadIdx.x * 4;
        float4 v;
        v.x = lacc[0][d4 + 0] + lacc[1][d4 + 0] + lacc[2][d4 + 0] + lacc[3][d4 + 0];
        v.y = lacc[0][d4 + 1] + lacc[1][d4 + 1] + lacc[2][d4 + 1] + lacc[3][d4 + 1];
        v.z = lacc[0][d4 + 2] + lacc[1][d4 + 2] + lacc[2][d4 + 2] + lacc[3][d4 + 2];
        v.w = lacc[0][d4 + 3] + lacc[1][d4 + 3] + lacc[2][d4 + 3] + lacc[3][d4 + 3];
        *(float4*)(part + (size_t)bid * D + d4) = v;
    }
}

// ---------------- Kernel R: y[b,d] = (1/S) * sum_c part[b*CHUNKS+c][d]
// grid = 32 b * 3 d-segments = 96 blocks, 256 threads, thread = one d.
__global__ __launch_bounds__(256)
void reduce_partials_kernel(const float* __restrict__ part, float* __restrict__ y) {
    const int b    = blockIdx.x / 3;
    const int dseg = blockIdx.x % 3;
    const int d    = dseg * 256 + threadIdx.x;

    const float* pb = part + (size_t)b * CHUNKS * D + d;
    float s = 0.0f;
#pragma unroll
    for (int c = 0; c < CHUNKS; ++c) s += pb[(size_t)c * D];
    y[b * D + d] = s * (1.0f / (float)S);
}

// ---------------- Kernel B: out[b,o] = (y[b,:] . p[o,:]) / max(||p[o,:]||, eps)
// Thread = (b in 0..31, oj in 0..3, h in 0..1). h splits D into two 384-halves;
// adjacent lanes (h=0/1) combine via __shfl_xor(.,1). p-row ssq computed
// redundantly in-register (data already loaded), so no separate norm pass.
static constexpr int OJ = 4;            // o-rows per block -> grid = 2048/4 = 512
static constexpr int HALF = D / 2;      // 384

__global__ __launch_bounds__(256)
void proj_kernel(const float* __restrict__ p, const float* __restrict__ y,
                 float* __restrict__ out) {
    const int o0  = blockIdx.x * OJ;
    const int tid = threadIdx.x;
    const int h   = tid & 1;
    const int oj  = (tid >> 1) & (OJ - 1);
    const int b   = tid >> 3;

    const float* prow = p + (size_t)(o0 + oj) * D + h * HALF;
    const float* yrow = y + (size_t)b * D + h * HALF;

    float dot = 0.0f, sp = 0.0f;
#pragma unroll 8
    for (int d = 0; d < HALF; d += 4) {
        const float4 pv = *(const float4*)(prow + d);
        const float4 yv = *(const float4*)(yrow + d);
        dot += pv.x * yv.x + pv.y * yv.y + pv.z * yv.z + pv.w * yv.w;
        sp  += pv.x * pv.x + pv.y * pv.y + pv.z * pv.z + pv.w * pv.w;
    }

    dot += __shfl_xor(dot, 1);
    sp  += __shfl_xor(sp, 1);

    if (h == 0) {
        out[b * O + (o0 + oj)] = dot / fmaxf(sqrtf(sp), EPS_F);
    }
}

extern "C" void kernel_launch(void* const* d_in, const int* in_sizes, int n_in,
                              void* d_out, int out_size, void* d_ws, size_t ws_size,
                              hipStream_t stream) {
    const float* x = (const float*)d_in[0];   // [32, 512, 768] fp32
    const float* p = (const float*)d_in[1];   // [2048, 768] fp32
    float* out = (float*)d_out;               // [32, 2048] fp32

    // ws layout: y[32*768] then part[1024*768]; every byte consumed is
    // written first (no init / memset needed despite 0xAA poison).
    float* y    = (float*)d_ws;
    float* part = y + (size_t)B * D;

    mean_norm_partial_kernel<<<B * CHUNKS, 256, 0, stream>>>(x, part);
    reduce_partials_kernel<<<B * 3, 256, 0, stream>>>(part, y);
    proj_kernel<<<O / OJ, 256, 0, stream>>>(p, y, out);
}

// Round 3
// 95.999 us; speedup vs baseline: 1.3050x; 1.2489x over previous
//
#include <hip/hip_runtime.h>

#define EPS_F 1e-8f

static constexpr int B = 32;
static constexpr int S = 512;
static constexpr int D = 768;
static constexpr int O = 2048;

// ---------------- Kernel A: partial sums of normalized rows.
// part[bid][d] = sum over this block's 16 rows of x[b,s,d] / max(||x[b,s]||, eps)
// One wave per token row (768 floats = 64 lanes x 12 = 3 x float4/lane).
// All 12 float4 loads issued up-front (max MLP), 4 independent shuffle-reduce
// chains, register accumulate, LDS combine, coalesced float4 store. No atomics.
static constexpr int ROWS_PER_BLOCK = 16;
static constexpr int CHUNKS = S / ROWS_PER_BLOCK;  // 32 -> grid = 32*32 = 1024 blocks

__global__ __launch_bounds__(256)
void mean_norm_partial_kernel(const float* __restrict__ x, float* __restrict__ part) {
    const int bid  = blockIdx.x;
    const int b    = bid / CHUNKS;
    const int c    = bid % CHUNKS;
    const int wave = threadIdx.x >> 6;
    const int lane = threadIdx.x & 63;

    const float* xb = x + ((size_t)b * S + (size_t)c * ROWS_PER_BLOCK) * D;

    // Load all 4 assigned rows (12 float4 loads in flight before any use).
    float vv[4][12];
#pragma unroll
    for (int rr = 0; rr < 4; ++rr) {
        const float* row = xb + (size_t)(rr * 4 + wave) * D + lane * 4;
#pragma unroll
        for (int k = 0; k < 3; ++k) {
            const float4 t = *(const float4*)(row + k * 256);
            vv[rr][k * 4 + 0] = t.x; vv[rr][k * 4 + 1] = t.y;
            vv[rr][k * 4 + 2] = t.z; vv[rr][k * 4 + 3] = t.w;
        }
    }

    // 4 independent ssq butterfly reductions (compiler interleaves the chains).
    float inv[4];
#pragma unroll
    for (int rr = 0; rr < 4; ++rr) {
        float ssq = 0.0f;
#pragma unroll
        for (int j = 0; j < 12; ++j) ssq += vv[rr][j] * vv[rr][j];
#pragma unroll
        for (int off = 1; off < 64; off <<= 1) ssq += __shfl_xor(ssq, off);
        inv[rr] = 1.0f / fmaxf(sqrtf(ssq), EPS_F);
    }

    float racc[12];
#pragma unroll
    for (int j = 0; j < 12; ++j)
        racc[j] = vv[0][j] * inv[0] + vv[1][j] * inv[1]
                + vv[2][j] * inv[2] + vv[3][j] * inv[3];

    __shared__ float lacc[4][D];
#pragma unroll
    for (int k = 0; k < 3; ++k) {
        float4 v = make_float4(racc[k * 4 + 0], racc[k * 4 + 1],
                               racc[k * 4 + 2], racc[k * 4 + 3]);
        *(float4*)&lacc[wave][k * 256 + lane * 4] = v;
    }
    __syncthreads();

    // threads 0..191: each writes one float4 (192*4 = 768), coalesced.
    if (threadIdx.x < D / 4) {
        const int d4 = threadIdx.x * 4;
        float4 v;
        v.x = lacc[0][d4 + 0] + lacc[1][d4 + 0] + lacc[2][d4 + 0] + lacc[3][d4 + 0];
        v.y = lacc[0][d4 + 1] + lacc[1][d4 + 1] + lacc[2][d4 + 1] + lacc[3][d4 + 1];
        v.z = lacc[0][d4 + 2] + lacc[1][d4 + 2] + lacc[2][d4 + 2] + lacc[3][d4 + 2];
        v.w = lacc[0][d4 + 3] + lacc[1][d4 + 3] + lacc[2][d4 + 3] + lacc[3][d4 + 3];
        *(float4*)(part + (size_t)bid * D + d4) = v;
    }
}

// ---------------- Kernel R: y[b,d] = (1/S) * sum_c part[b*CHUNKS+c][d]
// grid = 32 b * 3 d-segments = 96 blocks, 256 threads, thread = one d.
__global__ __launch_bounds__(256)
void reduce_partials_kernel(const float* __restrict__ part, float* __restrict__ y) {
    const int b    = blockIdx.x / 3;
    const int dseg = blockIdx.x % 3;
    const int d    = dseg * 256 + threadIdx.x;

    const float* pb = part + (size_t)b * CHUNKS * D + d;
    float s = 0.0f;
#pragma unroll
    for (int c = 0; c < CHUNKS; ++c) s += pb[(size_t)c * D];
    y[b * D + d] = s * (1.0f / (float)S);
}

// ---------------- Kernel B: out[b,o] = (y[b,:] . p[o,:]) / max(||p[o,:]||, eps)
// One WAVE per p-row: 64 lanes x 12 floats = fully coalesced 1KB p loads,
// ssq in-register + butterfly. y staged in LDS (16 b-rows = 48 KB; grid.y
// selects the b-half, so p is read twice from HBM = +6.3 MB, still small).
// Per wave: 16 dots against LDS y rows (ds_read_b128), 16 butterfly reduces.
static constexpr int BH = 16;                 // b-rows per block (half of B)
static constexpr int OW = 8;                  // o-rows (waves) per block

__global__ __launch_bounds__(512)
void proj_kernel(const float* __restrict__ p, const float* __restrict__ y,
                 float* __restrict__ out) {
    __shared__ float ylds[BH * D];            // 16*768*4 = 49152 B

    const int half = blockIdx.y;              // 0 or 1
    const int tid  = threadIdx.x;

    // Stage this half's y rows: 512 threads x 6 float4 = 12288 floats, coalesced.
    const float* ysrc = y + (size_t)half * BH * D;
#pragma unroll
    for (int i = 0; i < (BH * D) / (512 * 4); ++i) {  // 6 iterations
        const int f4 = i * 512 + tid;
        *(float4*)&ylds[f4 * 4] = *(const float4*)&ysrc[f4 * 4];
    }
    __syncthreads();

    const int wave = tid >> 6;
    const int lane = tid & 63;
    const int o    = blockIdx.x * OW + wave;

    // Load p row (coalesced), compute inv-norm, pre-scale fragments.
    const float* prow = p + (size_t)o * D + lane * 4;
    float4 pv[3];
#pragma unroll
    for (int k = 0; k < 3; ++k) pv[k] = *(const float4*)(prow + k * 256);

    float ssq = 0.0f;
#pragma unroll
    for (int k = 0; k < 3; ++k)
        ssq += pv[k].x * pv[k].x + pv[k].y * pv[k].y
             + pv[k].z * pv[k].z + pv[k].w * pv[k].w;
#pragma unroll
    for (int off = 1; off < 64; off <<= 1) ssq += __shfl_xor(ssq, off);
    const float inv = 1.0f / fmaxf(sqrtf(ssq), EPS_F);
#pragma unroll
    for (int k = 0; k < 3; ++k) {
        pv[k].x *= inv; pv[k].y *= inv; pv[k].z *= inv; pv[k].w *= inv;
    }

    // 16 dots vs LDS y rows; 16 independent butterfly chains (ILP).
    float tot[BH];
#pragma unroll
    for (int b = 0; b < BH; ++b) {
        const float* yb = &ylds[b * D + lane * 4];
        float acc = 0.0f;
#pragma unroll
        for (int k = 0; k < 3; ++k) {
            const float4 yv = *(const float4*)(yb + k * 256);
            acc += pv[k].x * yv.x + pv[k].y * yv.y
                 + pv[k].z * yv.z + pv[k].w * yv.w;
        }
        tot[b] = acc;
    }
#pragma unroll
    for (int b = 0; b < BH; ++b) {
#pragma unroll
        for (int off = 1; off < 64; off <<= 1) tot[b] += __shfl_xor(tot[b], off);
    }

    if (lane == 0) {
#pragma unroll
        for (int b = 0; b < BH; ++b)
            out[(size_t)(half * BH + b) * O + o] = tot[b];
    }
}

extern "C" void kernel_launch(void* const* d_in, const int* in_sizes, int n_in,
                              void* d_out, int out_size, void* d_ws, size_t ws_size,
                              hipStream_t stream) {
    const float* x = (const float*)d_in[0];   // [32, 512, 768] fp32
    const float* p = (const float*)d_in[1];   // [2048, 768] fp32
    float* out = (float*)d_out;               // [32, 2048] fp32

    // ws layout: y[32*768] then part[1024*768]; every byte consumed is
    // written first (no init / memset needed despite 0xAA poison).
    float* y    = (float*)d_ws;
    float* part = y + (size_t)B * D;

    mean_norm_partial_kernel<<<B * CHUNKS, 256, 0, stream>>>(x, part);
    reduce_partials_kernel<<<B * 3, 256, 0, stream>>>(part, y);
    proj_kernel<<<dim3(O / OW, 2), 512, 0, stream>>>(p, y, out);
}